// Round 12
// baseline (96.266 us; speedup 1.0000x reference)
//
#include <hip/hip_runtime.h>

#define NBINS 101
#define NB2 (2 * NBINS)    // 202 bins total (pos + neg)
#define NTHREADS 256
#define NCOPY 32           // histogram replicas, one per lane&31 (bank = copy)
#define CNT_SHIFT 22
#define QMAX 413695u       // (100<<12) | 4095 : clamps idx to <= 100
#define GSHIFT 38          // global u64 packing: (count << 38) | frac_q12
#define NREP 32            // global accumulator replicas
#define FSCALE 452.5483399593904f   // sqrt(50 * 4096): folds (s+1)*204800 into MFMA

typedef _Float16 half8 __attribute__((ext_vector_type(8)));
typedef float floatx4 __attribute__((ext_vector_type(4)));

// ---------------------------------------------------------------------------
// R21: node-deletion round (revert R20; single structural change vs R15).
// R20 post-mortem: 2x waves/SIMD -> +9us. Hist internals are now measured
// insensitive-to-negative on ALL axes (R14 atomics null, R15 traffic +1.1,
// R20 occupancy -9). Budget: 40.4 fill + 21.2 hist (R19) + ~2-5 convert +
// ~3 finalize + ~12-17 GAPS. Only legal gap lever: fewer nodes.
// Change: delete the convert kernel (3 nodes -> 2). Hist loads f32 feats and
// converts in-register per fragment — identical (_Float16)(f*FSCALE) ops ->
// bit-identical -> absmax 0.0. gH moves to a module __device__ global:
// .bss = zeroed at load (first run correct); finalize re-zeroes after
// reading (self-restoring invariant across graph replays; harness poison
// only hits d_ws, now unused). Priced risk: R8's f32-direct regression was
// in the 64x64/2080-block config (2x redundancy, confounded floor); here
// +84MB L2 (~+2.4us, R15 says traffic ~free) + ~0.5us cvt VALU vs saving
// one dispatch + one gap (~6-9us).
// ---------------------------------------------------------------------------

__device__ unsigned long long gHist[NREP * NB2];  // .bss: zero at module load

static __device__ __forceinline__ half8 cvt_frag(const float* p) {
    float4 a = *(const float4*)p;
    float4 b = *(const float4*)(p + 4);
    half8 h;
    h[0] = (_Float16)(a.x * FSCALE); h[1] = (_Float16)(a.y * FSCALE);
    h[2] = (_Float16)(a.z * FSCALE); h[3] = (_Float16)(a.w * FSCALE);
    h[4] = (_Float16)(b.x * FSCALE); h[5] = (_Float16)(b.y * FSCALE);
    h[6] = (_Float16)(b.z * FSCALE); h[7] = (_Float16)(b.w * FSCALE);
    return h;
}

// ---------------------------------------------------------------------------
// One 128x128 upper-triangular tile per BLOCK (R15 structure, 4 waves); f32
// fragment loads + in-register FSCALE*cvt; acc in q-space (bias pre-added);
// one ds_add_u32 per pair; per-block unpack -> one u64 atomicAdd per bin.
// ---------------------------------------------------------------------------
__global__ __launch_bounds__(NTHREADS, 4)
void hist_pairs_kernel(const float* __restrict__ feats,
                       const int* __restrict__ classes,
                       int ntiles) {
    __shared__ unsigned lhist[NB2][NCOPY];    // packed count|frac, 25.9 KB
    __shared__ __align__(16) int cls[2][128]; // [A/B][row]

    const int tid = threadIdx.x;
    const int wave = tid >> 6;
    const int lane = tid & 63;

    // zero local histograms (uint4 stores: 1616 x 16B / 256 thr)
    {
        uint4* z = (uint4*)&lhist[0][0];
        uint4 zero = {0u, 0u, 0u, 0u};
        for (int t = tid; t < NB2 * NCOPY / 4; t += NTHREADS) z[t] = zero;
    }

    // decode block -> upper-triangular tile (ti, tj), ntiles = 32
    int ti = 0, tj = 0;
    {
        int rem = blockIdx.x;
        while (rem >= ntiles - ti) { rem -= ntiles - ti; ++ti; }
        tj = ti + rem;
    }
    if (tid < 128)  cls[0][tid]       = classes[ti * 128 + tid];
    else            cls[1][tid - 128] = classes[tj * 128 + (tid - 128)];
    __syncthreads();

    {
        const int i0 = ti * 128, j0 = tj * 128;
        const int lr = lane & 15;
        const int quad = lane >> 4;

        // wave-private A strip (32 rows), block-shared B tile (128 cols)
        const float* Ab = feats + (size_t)(i0 + wave * 32 + lr) * 128 + quad * 8;
        const float* Bb = feats + (size_t)(j0 + lr) * 128 + quad * 8;

        // acc initialized to the binning bias: (s+1)*204800 + 0.5 rounding
        floatx4 acc[2][8];
        #pragma unroll
        for (int mi = 0; mi < 2; ++mi)
            #pragma unroll
            for (int ni = 0; ni < 8; ++ni) {
                acc[mi][ni][0] = 204800.5f; acc[mi][ni][1] = 204800.5f;
                acc[mi][ni][2] = 204800.5f; acc[mi][ni][3] = 204800.5f;
            }

        #pragma unroll
        for (int ks = 0; ks < 128; ks += 32) {
            half8 af[2];
            #pragma unroll
            for (int mi = 0; mi < 2; ++mi)
                af[mi] = cvt_frag(Ab + (size_t)mi * 16 * 128 + ks);
            half8 bf[8];
            #pragma unroll
            for (int ni = 0; ni < 8; ++ni)
                bf[ni] = cvt_frag(Bb + (size_t)ni * 16 * 128 + ks);
            #pragma unroll
            for (int mi = 0; mi < 2; ++mi)
                #pragma unroll
                for (int ni = 0; ni < 8; ++ni)
                    acc[mi][ni] = __builtin_amdgcn_mfma_f32_16x16x32_f16(
                        af[mi], bf[ni], acc[mi][ni], 0, 0, 0);
        }

        // classes for this lane's C fragment rows/cols
        int cA[2][4], cB[8];
        #pragma unroll
        for (int mi = 0; mi < 2; ++mi) {
            int4 c4 = *(const int4*)&cls[0][wave * 32 + mi * 16 + quad * 4];
            cA[mi][0] = c4.x; cA[mi][1] = c4.y;
            cA[mi][2] = c4.z; cA[mi][3] = c4.w;
        }
        #pragma unroll
        for (int ni = 0; ni < 8; ++ni) cB[ni] = cls[1][ni * 16 + lr];

        // binning: acc already equals q + tiny fp noise. One ds_add_u32/pair.
        const int copy = lane & (NCOPY - 1);
        unsigned* hb = &lhist[0][0] + copy;
        const bool diag = (ti == tj);
        #pragma unroll
        for (int mi = 0; mi < 2; ++mi) {
            #pragma unroll
            for (int ni = 0; ni < 8; ++ni) {
                #pragma unroll
                for (int r = 0; r < 4; ++r) {
                    const int li = wave * 32 + mi * 16 + quad * 4 + r;
                    const int lj = ni * 16 + lr;
                    if (diag && li >= lj) continue;  // strict upper triangle
                    float qf = fmaxf(acc[mi][ni][r], 0.0f);
                    unsigned q = (unsigned)qf;
                    q = q > QMAX ? QMAX : q;
                    unsigned idx = q >> 12;
                    unsigned word = (q & 4095u) | (1u << CNT_SHIFT);
                    unsigned hoff = (cA[mi][r] == cB[ni]) ? 0u : (unsigned)NBINS;
                    atomicAdd(hb + (hoff + idx) * NCOPY, word);
                }
            }
        }
    }
    __syncthreads();

    // per-bin unpack: C = sum(w>>22), Fq = sum(w&mask) (q12 fixed point).
    // Max adds per (bin,copy) = 2 lanes * 64 pairs = 128 -> fields safe
    // (cnt <= 128 < 2^10, frac <= 128*4095 < 2^22).
    // Pack (C<<38)|Fq into one u64 atomicAdd; per-block Cs <= 16384 < 2^26,
    // Fq <= 6.7e7 < 2^38; global C 8.39e6 < 2^26, F 3.44e10 < 2^38.
    if (tid < NB2) {
        unsigned Cs = 0, Fq = 0;
        #pragma unroll
        for (int c = 0; c < NCOPY; ++c) {
            unsigned w = lhist[tid][(c + tid) & (NCOPY - 1)];
            Cs += w >> CNT_SHIFT;
            Fq += w & ((1u << CNT_SHIFT) - 1);
        }
        unsigned long long word =
            ((unsigned long long)Cs << GSHIFT) | (unsigned long long)Fq;
        atomicAdd(&gHist[(blockIdx.x & (NREP - 1)) * NB2 + tid], word);
    }
}

// ---------------------------------------------------------------------------
// Tiny finalize: sum 32 replica rows (52KB), unpack, telescope, fp64 cumsum.
// Then RE-ZERO gHist so the next graph replay starts from 0 (self-restoring
// invariant; first-ever run relies on .bss zero-init at module load).
// ---------------------------------------------------------------------------
__global__ __launch_bounds__(NTHREADS)
void finalize_kernel(float* __restrict__ out) {
    __shared__ double Cd[NB2];
    __shared__ double Fd[NB2];
    __shared__ double hd[NB2];
    const int t = threadIdx.x;
    if (t < NB2) {
        unsigned long long w = 0ull;
        #pragma unroll
        for (int r = 0; r < NREP; ++r) w += gHist[r * NB2 + t];
        Cd[t] = (double)(w >> GSHIFT);
        Fd[t] = (double)(w & ((1ull << GSHIFT) - 1)) * (1.0 / 4096.0);
    }
    __syncthreads();   // all gHist reads complete before re-zeroing
    for (int z = t; z < NREP * NB2; z += NTHREADS) gHist[z] = 0ull;
    if (t < NB2) {
        const int lo = (t < NBINS) ? 0 : NBINS;
        const int hi = lo + NBINS - 1;
        double h = Cd[t];
        if (t < hi) h -= Fd[t];
        if (t > lo) h += Fd[t - 1];
        hd[t] = h;
    }
    __syncthreads();
    if (t == 0) {
        double sp = 0.0, sn = 0.0;
        for (int k = 0; k < NBINS; ++k) { sp += hd[k]; sn += hd[NBINS + k]; }
        double isp = 1.0 / sp, isn = 1.0 / sn;
        double cdf = 0.0, res = 0.0;
        for (int k = 0; k < NBINS; ++k) {
            cdf += hd[k] * isp;                   // inclusive cumsum of pos
            res += hd[NBINS + k] * isn * cdf;     // dot with neg
        }
        out[0] = (float)res;
    }
}

extern "C" void kernel_launch(void* const* d_in, const int* in_sizes, int n_in,
                              void* d_out, int out_size, void* d_ws, size_t ws_size,
                              hipStream_t stream) {
    const float* feats   = (const float*)d_in[0];
    const int*   classes = (const int*)d_in[1];
    float* out = (float*)d_out;

    int N = in_sizes[1];                       // 4096
    int ntiles = N / 128;                      // 32
    int nblocks = ntiles * (ntiles + 1) / 2;   // 528 blocks, one tile each
    (void)d_ws; (void)ws_size;                 // workspace unused (gHist is a
                                               // module global, self-zeroing)

    hist_pairs_kernel<<<nblocks, NTHREADS, 0, stream>>>(feats, classes, ntiles);
    finalize_kernel<<<1, NTHREADS, 0, stream>>>(out);
}